// Round 1
// 729.433 us; speedup vs baseline: 1.0198x; 1.0198x over previous
//
#include <hip/hip_runtime.h>

// NCEAverage: scores[b,k] = exp(dot(memory[idx'[b,k]], x[b]) / T); out = scores / Z
// where idx'[:,0] = y, Z = mean(scores) * N.
// B=256, K=4096, D=128, N=1e6, T=0.07. Memory-bound: ~512 MB of gathered rows.
//
// v2 changes vs v1 (theory: break idx->row dependent-load chain, batch row loads,
// vectorize out stores):
//  - block's 64 indices preloaded to LDS (coalesced, y-substitution done there)
//  - each 32-lane group owns 8 CONSECUTIVE k's; all 8 row loads issued before
//    any reduction (16 dwordx4 in flight per wave)
//  - lane 0 writes 2x float4 (32 B contiguous) instead of 8 scattered dwords

constexpr int Bc = 256;
constexpr int Kc = 4096;
constexpr int Dc = 128;
constexpr long long Nc = 1000000;
constexpr int KPB = 64;          // k's per block; grid = (K/KPB, B)

__global__ __launch_bounds__(256) void nce_scores(
    const float* __restrict__ x, const int* __restrict__ y,
    const int* __restrict__ idxp, const float* __restrict__ memory,
    float* __restrict__ out, double* __restrict__ partial)
{
    __shared__ float  xs[Dc];
    __shared__ int    inds[KPB];
    __shared__ double bsum[8];

    const int b     = blockIdx.y;
    const int tid   = threadIdx.x;
    const int kbase = blockIdx.x * KPB;

    // stage x[b] (512 B) and the block's 64 indices in LDS
    if (tid < Dc / 4) {
        ((float4*)xs)[tid] = ((const float4*)(x + (long)b * Dc))[tid];
    } else if (tid >= 64 && tid < 64 + KPB) {
        const int j  = tid - 64;
        const int kk = kbase + j;
        // column 0 of idx is forced to the positive index y[b]
        inds[j] = (kk == 0) ? y[b] : idxp[(long)b * Kc + kk];
    }
    __syncthreads();

    const int group = tid >> 5;   // 0..7 (8 groups of 32 lanes)
    const int lane  = tid & 31;
    const float4 xf = ((const float4*)xs)[lane];

    // 8 consecutive k's per group
    int rows[8];
#pragma unroll
    for (int it = 0; it < 8; ++it) rows[it] = inds[group * 8 + it];

    // issue all 8 row loads (512 B each) before any compute
    float4 w[8];
#pragma unroll
    for (int it = 0; it < 8; ++it)
        w[it] = ((const float4*)(memory + (long)rows[it] * Dc))[lane];

    const float invT = 1.0f / 0.07f;
    float sc[8];
#pragma unroll
    for (int it = 0; it < 8; ++it) {
        float dot = w[it].x * xf.x + w[it].y * xf.y
                  + w[it].z * xf.z + w[it].w * xf.w;
        // butterfly reduce over the 32-lane group (masks <32 stay in-group on wave64)
#pragma unroll
        for (int m = 16; m >= 1; m >>= 1)
            dot += __shfl_xor(dot, m, 64);
        sc[it] = expf(dot * invT);
    }

    if (lane == 0) {
        float4 o0 = make_float4(sc[0], sc[1], sc[2], sc[3]);
        float4 o1 = make_float4(sc[4], sc[5], sc[6], sc[7]);
        float* op = out + (long)b * Kc + kbase + group * 8;
        ((float4*)op)[0] = o0;
        ((float4*)op)[1] = o1;
        double s = 0.0;
#pragma unroll
        for (int i = 0; i < 8; ++i) s += (double)sc[i];
        bsum[group] = s;
    }
    __syncthreads();
    if (tid == 0) {
        double s = 0.0;
#pragma unroll
        for (int g = 0; g < 8; ++g) s += bsum[g];
        // spread contention over 8 cells; 2048 atomics per cell
        unsafeAtomicAdd(&partial[blockIdx.x & 7], s);
    }
}

// Phase 2: out *= (B*K) / (N * sum)
__global__ __launch_bounds__(256) void nce_norm(
    float* __restrict__ out, const double* __restrict__ partial)
{
    double s = 0.0;
#pragma unroll
    for (int g = 0; g < 8; ++g) s += partial[g];
    const float scale = (float)((double)((long long)Bc * Kc) / ((double)Nc * s));
    const int i = blockIdx.x * blockDim.x + threadIdx.x;
    float4 v = ((float4*)out)[i];
    v.x *= scale; v.y *= scale; v.z *= scale; v.w *= scale;
    ((float4*)out)[i] = v;
}

extern "C" void kernel_launch(void* const* d_in, const int* in_sizes, int n_in,
                              void* d_out, int out_size, void* d_ws, size_t ws_size,
                              hipStream_t stream) {
    const float* x      = (const float*)d_in[0];
    const int*   y      = (const int*)  d_in[1];
    const int*   idx    = (const int*)  d_in[2];
    const float* memory = (const float*)d_in[3];
    float*  out     = (float*)d_out;
    double* partial = (double*)d_ws;

    hipMemsetAsync(partial, 0, 8 * sizeof(double), stream);

    dim3 g1(Kc / KPB, Bc);
    nce_scores<<<g1, 256, 0, stream>>>(x, y, idx, memory, out, partial);

    const int n4 = Bc * Kc / 4;                  // 262144 float4 elements
    nce_norm<<<n4 / 256, 256, 0, stream>>>(out, partial);
}

// Round 3
// 658.173 us; speedup vs baseline: 1.1303x; 1.1083x over previous
//
#include <hip/hip_runtime.h>

// NCEAverage: scores[b,k] = exp(dot(memory[idx'[b,k]], x[b]) / T); out = scores / Z
// where idx'[:,0] = y, Z = mean(scores) * N.
// B=256, K=4096, D=128, N=1e6, T=0.07. Memory-bound: ~430 MB unique gathered rows.
//
// v3 (resubmit; previous round was an infra failure, not a kernel verdict):
//  - KPB 64 -> 128: each 32-lane group owns 16 consecutive k's; all 16 row
//    loads (16 KB/wave in flight) issued before any reduction
//  - lane 0 writes 4x float4 (64 B contiguous) per group

constexpr int Bc = 256;
constexpr int Kc = 4096;
constexpr int Dc = 128;
constexpr long long Nc = 1000000;
constexpr int KPB = 128;         // k's per block; grid = (K/KPB, B)
constexpr int KPG = KPB / 8;     // 16 k's per 32-lane group

__global__ __launch_bounds__(256) void nce_scores(
    const float* __restrict__ x, const int* __restrict__ y,
    const int* __restrict__ idxp, const float* __restrict__ memory,
    float* __restrict__ out, double* __restrict__ partial)
{
    __shared__ float  xs[Dc];
    __shared__ int    inds[KPB];
    __shared__ double bsum[8];

    const int b     = blockIdx.y;
    const int tid   = threadIdx.x;
    const int kbase = blockIdx.x * KPB;

    // stage x[b] (512 B) and the block's 128 indices in LDS
    if (tid < Dc / 4) {
        ((float4*)xs)[tid] = ((const float4*)(x + (long)b * Dc))[tid];
    } else if (tid >= 128) {
        const int j  = tid - 128;
        const int kk = kbase + j;
        // column 0 of idx is forced to the positive index y[b]
        inds[j] = (kk == 0) ? y[b] : idxp[(long)b * Kc + kk];
    }
    __syncthreads();

    const int group = tid >> 5;   // 0..7 (8 groups of 32 lanes)
    const int lane  = tid & 31;
    const float4 xf = ((const float4*)xs)[lane];

    // 16 consecutive k's per group
    int rows[KPG];
#pragma unroll
    for (int it = 0; it < KPG; ++it) rows[it] = inds[group * KPG + it];

    // issue all 16 row loads (512 B each; 16 KB per wave) before any compute
    float4 w[KPG];
#pragma unroll
    for (int it = 0; it < KPG; ++it)
        w[it] = ((const float4*)(memory + (long)rows[it] * Dc))[lane];

    const float invT = 1.0f / 0.07f;
    float sc[KPG];
#pragma unroll
    for (int it = 0; it < KPG; ++it) {
        float dot = w[it].x * xf.x + w[it].y * xf.y
                  + w[it].z * xf.z + w[it].w * xf.w;
        // butterfly reduce over the 32-lane group (masks <32 stay in-group on wave64)
#pragma unroll
        for (int m = 16; m >= 1; m >>= 1)
            dot += __shfl_xor(dot, m, 64);
        sc[it] = expf(dot * invT);
    }

    if (lane == 0) {
        float* op = out + (long)b * Kc + kbase + group * KPG;
#pragma unroll
        for (int q = 0; q < KPG / 4; ++q)
            ((float4*)op)[q] = make_float4(sc[4*q], sc[4*q+1], sc[4*q+2], sc[4*q+3]);
        double s = 0.0;
#pragma unroll
        for (int i = 0; i < KPG; ++i) s += (double)sc[i];
        bsum[group] = s;
    }
    __syncthreads();
    if (tid == 0) {
        double s = 0.0;
#pragma unroll
        for (int g = 0; g < 8; ++g) s += bsum[g];
        // spread contention over 8 cells
        unsafeAtomicAdd(&partial[blockIdx.x & 7], s);
    }
}

// Phase 2: out *= (B*K) / (N * sum)
__global__ __launch_bounds__(256) void nce_norm(
    float* __restrict__ out, const double* __restrict__ partial)
{
    double s = 0.0;
#pragma unroll
    for (int g = 0; g < 8; ++g) s += partial[g];
    const float scale = (float)((double)((long long)Bc * Kc) / ((double)Nc * s));
    const int i = blockIdx.x * blockDim.x + threadIdx.x;
    float4 v = ((float4*)out)[i];
    v.x *= scale; v.y *= scale; v.z *= scale; v.w *= scale;
    ((float4*)out)[i] = v;
}

extern "C" void kernel_launch(void* const* d_in, const int* in_sizes, int n_in,
                              void* d_out, int out_size, void* d_ws, size_t ws_size,
                              hipStream_t stream) {
    const float* x      = (const float*)d_in[0];
    const int*   y      = (const int*)  d_in[1];
    const int*   idx    = (const int*)  d_in[2];
    const float* memory = (const float*)d_in[3];
    float*  out     = (float*)d_out;
    double* partial = (double*)d_ws;

    hipMemsetAsync(partial, 0, 8 * sizeof(double), stream);

    dim3 g1(Kc / KPB, Bc);
    nce_scores<<<g1, 256, 0, stream>>>(x, y, idx, memory, out, partial);

    const int n4 = Bc * Kc / 4;                  // 262144 float4 elements
    nce_norm<<<n4 / 256, 256, 0, stream>>>(out, partial);
}